// Round 15
// baseline (75.369 us; speedup 1.0000x reference)
//
#include <hip/hip_runtime.h>
#include <math.h>

typedef short bf16x8 __attribute__((ext_vector_type(8)));
typedef float f32x4 __attribute__((ext_vector_type(4)));
typedef float f32x16 __attribute__((ext_vector_type(16)));
typedef unsigned short u16;
typedef unsigned int u32;

#define RFL(x) __builtin_amdgcn_readfirstlane(x)

static __device__ __forceinline__ float bf2f(u16 s) {
  union { u32 u; float f; } c; c.u = ((u32)s) << 16; return c.f;
}
static __device__ __forceinline__ u16 f2bf(float f) {
  union { float f; u32 u; } c; c.f = f;
  u32 u = c.u + 0x7fffu + ((c.u >> 16) & 1u);
  return (u16)(u >> 16);
}
static __device__ __forceinline__ u32 pk2(float lo, float hi) {
  u32 r;
  asm("v_cvt_pk_bf16_f32 %0, %1, %2" : "=v"(r) : "v"(lo), "v"(hi));
  return r;
}
static __device__ __forceinline__ f32x4 MF(bf16x8 a, bf16x8 b, f32x4 c) {
  return __builtin_amdgcn_mfma_f32_16x16x32_bf16(a, b, c, 0, 0, 0);
}
static __device__ __forceinline__ f32x16 MF32(bf16x8 a, bf16x8 b, f32x16 c) {
  return __builtin_amdgcn_mfma_f32_32x32x16_bf16(a, b, c, 0, 0, 0);
}

// B=16, D=64, L=1280, H=8, hd=8, WIN=5, DFF=128
// QKV[20480][384] bf16 cols: [0:64)Qloc(*sc) [64:128)Kloc [128:192)Vloc
//   [192:256)Qg(*sc*log2e*128)  (cols 256..383 unused in QKV buffer)
// KTg[(b*8+h)*1280 + row][8]: K-g PRE-PERMUTED (swap bits 2<->3 of in-32-
//   group token index; involution). VTg[(b*8+h)*8+d][1280]: V-g transposed.
// MFMA 32x32x16: A: m=l&31,k=8*(l>>5)+j ; B: k=8*(l>>5)+j,n=l&31
//   C/D: row=(r&3)+8*(r>>2)+4*(l>>5), col=l&31
// Magic-bias softmax (R12-proven): QK acc init = 1.5*2^23 + 16250.3, Q
// carries *128*log2e*scale; low 16 bits of S = bf16 pattern of 2^score.

// ====== K1: fused x-transpose + bf16 convert + QKV GEMM (R13-proven) ====
__global__ __launch_bounds__(256) void qkvx(
    const float* __restrict__ x, const float* __restrict__ lw_in,
    const float* __restrict__ gw_in, const float* __restrict__ lb_in,
    const float* __restrict__ gb_in, u16* __restrict__ QKV,
    u16* __restrict__ KTg, u16* __restrict__ VTg) {
  __shared__ __align__(16) float xs[32][68];
  __shared__ __align__(16) u16 XTs[32 * 64];   // XOR-swizzled [tok][d]
  const int t = threadIdx.x;
  const int b = blockIdx.x / 40, l0 = (blockIdx.x % 40) * 32;
  for (int i = t; i < 2048; i += 256) {
    const int d = i >> 5, tok = i & 31;
    xs[tok][d] = x[(b * 64 + d) * 1280 + l0 + tok];
  }
  __syncthreads();
  {
    const int tok = t >> 3, c8 = (t & 7) * 8;
    union { bf16x8 v; u32 u[4]; } o;
    const float* src = &xs[tok][c8];
    o.u[0] = pk2(src[0], src[1]); o.u[1] = pk2(src[2], src[3]);
    o.u[2] = pk2(src[4], src[5]); o.u[3] = pk2(src[6], src[7]);
    const int byteoff = (tok * 128 + c8 * 2) ^ ((tok & 7) << 4);
    *(bf16x8*)((char*)XTs + byteoff) = o.v;
  }
  __syncthreads();
  const int lane = t & 63, w = RFL(t >> 6);
  const int lr = lane & 15, lg = lane >> 4;
  const int n0 = w * 96;                        // 4 waves x 96 cols
  bf16x8 a[2][2];
#pragma unroll
  for (int mt = 0; mt < 2; ++mt)
#pragma unroll
    for (int ks = 0; ks < 2; ++ks) {
      const int row = mt * 16 + lr;
      const int abyte = (row * 128 + ks * 64 + lg * 16) ^ ((row & 7) << 4);
      a[mt][ks] = *(const bf16x8*)((char*)XTs + abyte);
    }
  const float* W32 = (n0 < 192) ? lw_in : gw_in;
  const int nb = (n0 < 192) ? n0 : n0 - 192;
  bf16x8 bb[6][2];
#pragma unroll
  for (int nt = 0; nt < 6; ++nt)
#pragma unroll
    for (int ks = 0; ks < 2; ++ks) {
      const float* src = W32 + (nb + nt * 16 + lr) * 64 + ks * 32 + lg * 8;
      const float4 f0 = *(const float4*)src;
      const float4 f1 = *(const float4*)(src + 4);
      union { bf16x8 v; u32 u[4]; } o;
      o.u[0] = pk2(f0.x, f0.y); o.u[1] = pk2(f0.z, f0.w);
      o.u[2] = pk2(f1.x, f1.y); o.u[3] = pk2(f1.z, f1.w);
      bb[nt][ks] = o.v;
    }
  f32x4 acc[2][6];
#pragma unroll
  for (int mt = 0; mt < 2; ++mt)
#pragma unroll
    for (int nt = 0; nt < 6; ++nt) {
      f32x4 z = {0.f, 0.f, 0.f, 0.f};
      acc[mt][nt] = z;
#pragma unroll
      for (int ks = 0; ks < 2; ++ks)
        acc[mt][nt] = MF(a[mt][ks], bb[nt][ks], acc[mt][nt]);
    }
#pragma unroll
  for (int nt = 0; nt < 6; ++nt) {
    const int col = n0 + nt * 16 + lr;
    const float bias = (col < 192) ? lb_in[col] : gb_in[col - 192];
    if (col < 256) {
      // local Q: 1/sqrt(8); global Q: 1/sqrt(8)*log2e*128 (magic-bias)
      const float scale = (col < 64) ? 0.35355339059327373f
                        : ((col >= 192) ? 65.29332172878775f : 1.f);
#pragma unroll
      for (int mt = 0; mt < 2; ++mt)
#pragma unroll
        for (int r = 0; r < 4; ++r) {
          const int row = b * 1280 + l0 + mt * 16 + 4 * lg + r;
          QKV[row * 384 + col] = f2bf((acc[mt][nt][r] + bias) * scale);
        }
    } else if (col < 320) {
      // K-global -> KTg, pre-permuted rows (swap lg bits = bit2<->3 swap)
      const int h = (col - 256) >> 3, d = (col - 256) & 7;
      const int lgp = ((lg & 1) << 1) | (lg >> 1);
#pragma unroll
      for (int mt = 0; mt < 2; ++mt)
#pragma unroll
        for (int r = 0; r < 4; ++r) {
          const int prow = l0 + mt * 16 + 4 * lgp + r;
          KTg[((b * 8 + h) * 1280 + prow) * 8 + d] =
              f2bf(acc[mt][nt][r] + bias);
        }
    } else {
      // V-global -> VTg transposed; pack 4 consecutive tokens per store
      const int h = (col - 320) >> 3, d = (col - 320) & 7;
      const int rowbase = ((b * 8 + h) * 8 + d) * 1280;
#pragma unroll
      for (int mt = 0; mt < 2; ++mt) {
        const int tok = l0 + mt * 16 + 4 * lg;
        uint2 pv;
        pv.x = pk2(acc[mt][nt][0] + bias, acc[mt][nt][1] + bias);
        pv.y = pk2(acc[mt][nt][2] + bias, acc[mt][nt][3] + bias);
        *(uint2*)(VTg + rowbase + tok) = pv;
      }
    }
  }
}

// ====== K2: fused attention launch =======================================
// grid (16,128) x 256:
//   bx < 10 : global attention, split-K, 2-iteration q-loop (256 q/block):
//             split = bx&1, qpair = bx>>1. Staged K/V reused across both
//             q-iterations -> staging traffic and prologue amortized 2x.
//   else lid<640 : local windowed attention
//   else         : tail-weight conversion fp32->bf16
__global__ __launch_bounds__(256) void attn(
    const u16* __restrict__ QKV, const u16* __restrict__ KTg,
    const u16* __restrict__ VTg, u16* __restrict__ AOl,
    float* __restrict__ OSUM, float* __restrict__ OACC8,
    const float* __restrict__ lw_out, const float* __restrict__ gw_out,
    const float* __restrict__ w1, const float* __restrict__ w2,
    u16* __restrict__ Wlout, u16* __restrict__ Wgout,
    u16* __restrict__ W1b, u16* __restrict__ W2b) {
  __shared__ __align__(16) u16 Klds[640 * 8];   // pre-permuted K rows
  __shared__ __align__(16) u16 VT[9 * 640];     // V^T d=0..7; row 8 = ones
  const int t = threadIdx.x;
  if (blockIdx.x < 10) {
    const int bh = blockIdx.y;
    const int b = bh >> 3, h = bh & 7;
    const int split = blockIdx.x & 1, qpair = blockIdx.x >> 1;  // 0..4
    const int k0 = split * 640;
    const uint4* Ksrc = (const uint4*)(KTg + (bh * 1280 + k0) * 8);
    uint4* K4 = (uint4*)Klds;
    for (int i = t; i < 640; i += 256) K4[i] = Ksrc[i];
    const uint4* Vsrc = (const uint4*)(VTg + bh * 8 * 1280);
    uint4* V4 = (uint4*)VT;
    for (int i = t; i < 640; i += 256) {
      const int d = i / 80, j = i % 80;
      V4[d * 80 + j] = Vsrc[d * 160 + split * 80 + j];
    }
    for (int l = t; l < 640; l += 256) VT[8 * 640 + l] = 0x3F80;  // ones
    __syncthreads();
    const int lane = t & 63, w = RFL(t >> 6);
    const int c = lane & 31, hi = lane >> 5;
    const float CM = 12582912.0f + 16250.3f;   // 1.5*2^23 + Schraudolph C
    const bf16x8 qz = {0, 0, 0, 0, 0, 0, 0, 0};
#pragma unroll
    for (int qt = 0; qt < 2; ++qt) {
      const int q = qpair * 256 + qt * 128 + w * 32 + c;
      const bf16x8 qv =
          *(const bf16x8*)(QKV + (b * 1280 + q) * 384 + 192 + h * 8);
      const bf16x8 qf = (hi == 0) ? qv : qz;   // zero k-dims 8..15
      const u16* kp = Klds + c * 8;            // A row c (2-lane bcast)
      const int vrow = (c < 8) ? c : 8;
      const u16* vp = VT + vrow * 640 + hi * 8;
      f32x16 oaccA, oaccB, cmagic;
#pragma unroll
      for (int i = 0; i < 16; ++i) {
        oaccA[i] = 0.f; oaccB[i] = 0.f; cmagic[i] = CM;
      }
      auto step = [&](f32x16& oacc) {
        bf16x8 kf = *(const bf16x8*)kp;        // 32 keys x dims 0..7
        f32x16 s = MF32(kf, qf, cmagic);       // 1.5*2^23 + C + 128*score
        union { f32x16 f; u32 b[16]; } sb; sb.f = s;
        union { u32 u[4]; bf16x8 v; } pb1, pb2;
        pb1.u[0] = __builtin_amdgcn_perm(sb.b[1], sb.b[0], 0x05040100);
        pb1.u[1] = __builtin_amdgcn_perm(sb.b[3], sb.b[2], 0x05040100);
        pb1.u[2] = __builtin_amdgcn_perm(sb.b[5], sb.b[4], 0x05040100);
        pb1.u[3] = __builtin_amdgcn_perm(sb.b[7], sb.b[6], 0x05040100);
        pb2.u[0] = __builtin_amdgcn_perm(sb.b[9], sb.b[8], 0x05040100);
        pb2.u[1] = __builtin_amdgcn_perm(sb.b[11], sb.b[10], 0x05040100);
        pb2.u[2] = __builtin_amdgcn_perm(sb.b[13], sb.b[12], 0x05040100);
        pb2.u[3] = __builtin_amdgcn_perm(sb.b[15], sb.b[14], 0x05040100);
        bf16x8 vf1 = *(const bf16x8*)vp;       // V^T keys +8hi+0..7
        oacc = MF32(vf1, pb1.v, oacc);
        bf16x8 vf2 = *(const bf16x8*)(vp + 16);
        oacc = MF32(vf2, pb2.v, oacc);
        kp += 256; vp += 32;
      };
#pragma unroll 2
      for (int jt2 = 0; jt2 < 10; ++jt2) {     // 20 key-tiles, dual acc
        step(oaccA);
        step(oaccB);
      }
      f32x16 oacc;
#pragma unroll
      for (int i = 0; i < 16; ++i) oacc[i] = oaccA[i] + oaccB[i];
      const int qi = bh * 1280 + q;
      if (hi == 0) OSUM[split * 163840 + qi] = oacc[4];  // partial denom
      f32x4 od = {oacc[0], oacc[1], oacc[2], oacc[3]};   // d = 4hi + r
      *(f32x4*)(OACC8 + split * 1310720 + qi * 8 + hi * 4) = od;
    }
    return;
  }
  const int lid = (blockIdx.x - 10) * 128 + blockIdx.y;
  if (lid < 640) {
    // ---- local windowed attention (WIN=5, Q pre-scaled) ----
    const int g = lid * 256 + t;
    const int qi = g % 5, h = (g / 5) & 7, wi = (g / 40) & 255, b = g / 10240;
    const int row = b * 1280 + wi * 5 + qi;
    float q[8];
    {
      bf16x8 qv = *(const bf16x8*)(QKV + row * 384 + h * 8);
#pragma unroll
      for (int d = 0; d < 8; ++d) q[d] = bf2f((u16)qv[d]);
    }
    float p[5], sum = 0.f;
#pragma unroll
    for (int j = 0; j < 5; ++j) {
      const int krow = b * 1280 + wi * 5 + j;
      bf16x8 kv = *(const bf16x8*)(QKV + krow * 384 + 64 + h * 8);
      float s = 0.f;
#pragma unroll
      for (int d = 0; d < 8; ++d) s = fmaf(q[d], bf2f((u16)kv[d]), s);
      p[j] = __expf(s); sum += p[j];
    }
    const float inv = 1.f / sum;
    float o[8] = {0, 0, 0, 0, 0, 0, 0, 0};
#pragma unroll
    for (int j = 0; j < 5; ++j) {
      const int vrow = b * 1280 + wi * 5 + j;
      bf16x8 vv = *(const bf16x8*)(QKV + vrow * 384 + 128 + h * 8);
#pragma unroll
      for (int d = 0; d < 8; ++d) o[d] = fmaf(p[j], bf2f((u16)vv[d]), o[d]);
    }
    union { bf16x8 v; u32 u[4]; } ov;
    ov.u[0] = pk2(o[0] * inv, o[1] * inv); ov.u[1] = pk2(o[2] * inv, o[3] * inv);
    ov.u[2] = pk2(o[4] * inv, o[5] * inv); ov.u[3] = pk2(o[6] * inv, o[7] * inv);
    *(bf16x8*)(AOl + row * 64 + h * 8) = ov.v;
  } else if (lid < 736) {
    // ---- tail weight conversion ----
    const int f = (lid - 640) * 256 + t;
    if (f < 4096)       Wlout[f] = f2bf(lw_out[f]);
    else if (f < 8192)  Wgout[f - 4096] = f2bf(gw_out[f - 4096]);
    else if (f < 16384) W1b[f - 8192] = f2bf(w1[f - 8192]);
    else if (f < 24576) W2b[f - 16384] = f2bf(w2[f - 16384]);
  }
}

// ====== K3: combine splits + proj+res+LN (x2) + gate + FFN + LN3 =========
__global__ __launch_bounds__(64) void tail_kernel(
    const u16* __restrict__ AOl,
    const float* __restrict__ OSUM, const float* __restrict__ OACC8,
    const u16* __restrict__ Wlout, const u16* __restrict__ Wgout,
    const u16* __restrict__ W1b, const u16* __restrict__ W2b,
    const float* __restrict__ lb_out, const float* __restrict__ gb_out,
    const float* __restrict__ lwt,
    const float* __restrict__ g1, const float* __restrict__ b1,
    const float* __restrict__ g2, const float* __restrict__ b2,
    const float* __restrict__ g3, const float* __restrict__ b3,
    const float* __restrict__ bf1, const float* __restrict__ bf2,
    const float* __restrict__ x, float* __restrict__ out) {
  __shared__ __align__(16) float xso[64][20];   // residual in, out^T at end
  __shared__ __align__(16) u16 Ft[16 * 64];     // fused (XOR-swizzled)
  __shared__ __align__(16) u16 Ht[16 * 128];    // ffn hidden (XOR-swizzled)
  const int t = threadIdx.x;
  const int b = blockIdx.y, l0 = blockIdx.x * 16;
  for (int i = t; i < 1024; i += 64) {
    const int d = i >> 4, tok = i & 15;
    xso[d][tok] = x[(b * 64 + d) * 1280 + l0 + tok];
  }
  __syncthreads();
  const int lr = t & 15, lg = (t & 63) >> 4;
  const int grow = b * 1280 + l0;

  f32x4 accl[4], accg[4];
#pragma unroll
  for (int nt = 0; nt < 4; ++nt) { f32x4 z = {0,0,0,0}; accl[nt] = z; accg[nt] = z; }
#pragma unroll
  for (int ks = 0; ks < 2; ++ks) {
    bf16x8 al = *(const bf16x8*)(AOl + (grow + lr) * 64 + ks * 32 + lg * 8);
    const int h = ks * 4 + lg;
    const int qi = (b * 8 + h) * 1280 + l0 + lr;
    f32x4 oa0 = *(const f32x4*)(OACC8 + qi * 8);
    f32x4 oa1 = *(const f32x4*)(OACC8 + qi * 8 + 4);
    f32x4 ob0 = *(const f32x4*)(OACC8 + 1310720 + qi * 8);
    f32x4 ob1 = *(const f32x4*)(OACC8 + 1310720 + qi * 8 + 4);
    const float inv = 1.f / (OSUM[qi] + OSUM[163840 + qi]);
    union { bf16x8 v; u32 u[4]; } agv;
    agv.u[0] = pk2((oa0[0] + ob0[0]) * inv, (oa0[1] + ob0[1]) * inv);
    agv.u[1] = pk2((oa0[2] + ob0[2]) * inv, (oa0[3] + ob0[3]) * inv);
    agv.u[2] = pk2((oa1[0] + ob1[0]) * inv, (oa1[1] + ob1[1]) * inv);
    agv.u[3] = pk2((oa1[2] + ob1[2]) * inv, (oa1[3] + ob1[3]) * inv);
#pragma unroll
    for (int nt = 0; nt < 4; ++nt) {
      bf16x8 bl = *(const bf16x8*)(Wlout + (nt * 16 + lr) * 64 + ks * 32 + lg * 8);
      bf16x8 bg = *(const bf16x8*)(Wgout + (nt * 16 + lr) * 64 + ks * 32 + lg * 8);
      accl[nt] = MF(al, bl, accl[nt]);
      accg[nt] = MF(agv.v, bg, accg[nt]);
    }
  }
#pragma unroll
  for (int nt = 0; nt < 4; ++nt) {
    const int col = nt * 16 + lr;
    const float bl = lb_out[col], bg = gb_out[col];
    f32x4 xr = *(const f32x4*)&xso[col][lg * 4];
#pragma unroll
    for (int r = 0; r < 4; ++r) {
      accl[nt][r] += bl + xr[r];
      accg[nt][r] += bg + xr[r];
    }
  }
  auto LN = [&](f32x4* a, const float* gam, const float* bet) {
    float gv[4], bv[4];
#pragma unroll
    for (int nt = 0; nt < 4; ++nt) { gv[nt] = gam[nt * 16 + lr]; bv[nt] = bet[nt * 16 + lr]; }
#pragma unroll
    for (int r = 0; r < 4; ++r) {
      float s = a[0][r] + a[1][r] + a[2][r] + a[3][r];
      s += __shfl_xor(s, 1); s += __shfl_xor(s, 2);
      s += __shfl_xor(s, 4); s += __shfl_xor(s, 8);
      const float mu = s * 0.015625f;
      float q = 0.f;
#pragma unroll
      for (int nt = 0; nt < 4; ++nt) { const float cv = a[nt][r] - mu; q = fmaf(cv, cv, q); }
      q += __shfl_xor(q, 1); q += __shfl_xor(q, 2);
      q += __shfl_xor(q, 4); q += __shfl_xor(q, 8);
      const float rsq = rsqrtf(q * 0.015625f + 1e-5f);
#pragma unroll
      for (int nt = 0; nt < 4; ++nt)
        a[nt][r] = (a[nt][r] - mu) * rsq * gv[nt] + bv[nt];
    }
  };
  LN(accl, g1, b1);
  LN(accg, g2, b2);
  f32x4 fus[4];
#pragma unroll
  for (int nt = 0; nt < 4; ++nt) {
    const int col = nt * 16 + lr;
    const float al_ = 1.f / (1.f + __expf(-lwt[col]));
#pragma unroll
    for (int r = 0; r < 4; ++r)
      fus[nt][r] = al_ * accl[nt][r] + (1.f - al_) * accg[nt][r];
  }
#pragma unroll
  for (int nt = 0; nt < 4; ++nt)
#pragma unroll
    for (int r = 0; r < 4; ++r) {
      const int ltok = lg * 4 + r;
      const int byteoff = (ltok * 128 + (nt * 16 + lr) * 2) ^ ((ltok & 7) << 4);
      *(u16*)((char*)Ft + byteoff) = f2bf(fus[nt][r]);
    }
  asm volatile("" ::: "memory");
  __syncthreads();
  f32x4 hcc[8];
#pragma unroll
  for (int nt = 0; nt < 8; ++nt) { f32x4 z = {0,0,0,0}; hcc[nt] = z; }
#pragma unroll
  for (int ks = 0; ks < 2; ++ks) {
    const int abyte = (lr * 128 + ks * 64 + lg * 16) ^ ((lr & 7) << 4);
    bf16x8 af = *(const bf16x8*)((char*)Ft + abyte);
#pragma unroll
    for (int nt = 0; nt < 8; ++nt) {
      bf16x8 bw = *(const bf16x8*)(W1b + (nt * 16 + lr) * 64 + ks * 32 + lg * 8);
      hcc[nt] = MF(af, bw, hcc[nt]);
    }
  }
#pragma unroll
  for (int nt = 0; nt < 8; ++nt) {
    const int f = nt * 16 + lr;
    const float bbv = bf1[f];
#pragma unroll
    for (int r = 0; r < 4; ++r) {
      const float v = fmaxf(hcc[nt][r] + bbv, 0.f);
      const int ltok = lg * 4 + r;
      const int byteoff = (ltok * 256 + f * 2) ^ ((ltok & 7) << 4);
      *(u16*)((char*)Ht + byteoff) = f2bf(v);
    }
  }
  asm volatile("" ::: "memory");
  f32x4 occ[4];
#pragma unroll
  for (int nt = 0; nt < 4; ++nt) { f32x4 z = {0,0,0,0}; occ[nt] = z; }
#pragma unroll
  for (int ks = 0; ks < 4; ++ks) {
    const int abyte = (lr * 256 + ks * 64 + lg * 16) ^ ((lr & 7) << 4);
    bf16x8 af = *(const bf16x8*)((char*)Ht + abyte);
#pragma unroll
    for (int nt = 0; nt < 4; ++nt) {
      bf16x8 bw = *(const bf16x8*)(W2b + (nt * 16 + lr) * 128 + ks * 32 + lg * 8);
      occ[nt] = MF(af, bw, occ[nt]);
    }
  }
#pragma unroll
  for (int nt = 0; nt < 4; ++nt) {
    const float bb2 = bf2[nt * 16 + lr];
#pragma unroll
    for (int r = 0; r < 4; ++r) occ[nt][r] += bb2 + fus[nt][r];
  }
  LN(occ, g3, b3);
#pragma unroll
  for (int nt = 0; nt < 4; ++nt)
#pragma unroll
    for (int r = 0; r < 4; ++r)
      xso[nt * 16 + lr][lg * 4 + r] = occ[nt][r];
  __syncthreads();
  for (int i = t; i < 1024; i += 64) {
    const int d = i >> 4, tok = i & 15;
    out[(b * 64 + d) * 1280 + l0 + tok] = xso[d][tok];
  }
}

extern "C" void kernel_launch(void* const* d_in, const int* in_sizes, int n_in,
                              void* d_out, int out_size, void* d_ws,
                              size_t ws_size, hipStream_t stream) {
  const float* x      = (const float*)d_in[0];
  const float* lw_in  = (const float*)d_in[1];
  const float* lb_in  = (const float*)d_in[2];
  const float* lw_out = (const float*)d_in[3];
  const float* lb_out = (const float*)d_in[4];
  const float* gw_in  = (const float*)d_in[5];
  const float* gb_in  = (const float*)d_in[6];
  const float* gw_out = (const float*)d_in[7];
  const float* gb_out = (const float*)d_in[8];
  const float* lwt    = (const float*)d_in[9];
  const float* g1 = (const float*)d_in[10]; const float* b1 = (const float*)d_in[11];
  const float* g2 = (const float*)d_in[12]; const float* b2 = (const float*)d_in[13];
  const float* g3 = (const float*)d_in[14]; const float* b3 = (const float*)d_in[15];
  const float* w1 = (const float*)d_in[16]; const float* bf1 = (const float*)d_in[17];
  const float* w2 = (const float*)d_in[18]; const float* bf2 = (const float*)d_in[19];
  float* out = (float*)d_out;

  u16* QKV   = (u16*)d_ws;            // 7,864,320 u16
  u16* AOl   = QKV + 7864320;         // 1,310,720 u16
  u16* KTg   = AOl + 1310720;         // 1,310,720 u16
  u16* VTg   = KTg + 1310720;         // 1,310,720 u16
  u16* Wlout = VTg + 1310720;         // 4,096
  u16* Wgout = Wlout + 4096;          // 4,096
  u16* W1b   = Wgout + 4096;          // 8,192
  u16* W2b   = W1b + 8192;            // 8,192
  float* OSUM  = (float*)(W2b + 8192);    // 2 x 163,840 f32
  float* OACC8 = OSUM + 327680;           // 2 x 1,310,720 f32

  qkvx<<<dim3(640), dim3(256), 0, stream>>>(x, lw_in, gw_in, lb_in, gb_in,
                                            QKV, KTg, VTg);
  attn<<<dim3(16, 128), dim3(256), 0, stream>>>(QKV, KTg, VTg, AOl, OSUM,
                                                OACC8, lw_out, gw_out, w1, w2,
                                                Wlout, Wgout, W1b, W2b);
  tail_kernel<<<dim3(80, 16), dim3(64), 0, stream>>>(
      AOl, OSUM, OACC8, Wlout, Wgout, W1b, W2b, lb_out, gb_out, lwt,
      g1, b1, g2, b2, g3, b3, bf1, bf2, x, out);
}

// Round 16
// 63.792 us; speedup vs baseline: 1.1815x; 1.1815x over previous
//
#include <hip/hip_runtime.h>
#include <math.h>

typedef short bf16x8 __attribute__((ext_vector_type(8)));
typedef float f32x4 __attribute__((ext_vector_type(4)));
typedef float f32x16 __attribute__((ext_vector_type(16)));
typedef unsigned short u16;
typedef unsigned int u32;

#define RFL(x) __builtin_amdgcn_readfirstlane(x)

static __device__ __forceinline__ float bf2f(u16 s) {
  union { u32 u; float f; } c; c.u = ((u32)s) << 16; return c.f;
}
static __device__ __forceinline__ u16 f2bf(float f) {
  union { float f; u32 u; } c; c.f = f;
  u32 u = c.u + 0x7fffu + ((c.u >> 16) & 1u);
  return (u16)(u >> 16);
}
static __device__ __forceinline__ u32 pk2(float lo, float hi) {
  u32 r;
  asm("v_cvt_pk_bf16_f32 %0, %1, %2" : "=v"(r) : "v"(lo), "v"(hi));
  return r;
}
static __device__ __forceinline__ f32x4 MF(bf16x8 a, bf16x8 b, f32x4 c) {
  return __builtin_amdgcn_mfma_f32_16x16x32_bf16(a, b, c, 0, 0, 0);
}
static __device__ __forceinline__ f32x16 MF32(bf16x8 a, bf16x8 b, f32x16 c) {
  return __builtin_amdgcn_mfma_f32_32x32x16_bf16(a, b, c, 0, 0, 0);
}

// B=16, D=64, L=1280, H=8, hd=8, WIN=5, DFF=128
// QKV[20480][384] bf16 cols: [0:64)Qloc(*sc) [64:128)Kloc [128:192)Vloc
//   [192:256)Qg(*sc*log2e*128)  (cols 256..383 unused in QKV buffer)
// KTg[(b*8+h)*1280 + row][8]: K-g PRE-PERMUTED (swap bits 2<->3 of in-32-
//   group token index; involution). VTg[(b*8+h)*8+d][1280]: V-g transposed.
// MFMA 32x32x16: A: m=l&31,k=8*(l>>5)+j ; B: k=8*(l>>5)+j,n=l&31
//   C/D: row=(r&3)+8*(r>>2)+4*(l>>5), col=l&31
// Magic-bias softmax (R12-proven): QK acc init = 1.5*2^23 + 16250.3, Q
// carries *128*log2e*scale; low 16 bits of S = bf16 pattern of 2^score.
// R16: VT stride 648 u16 (1296 B -> rows start at banks 0,4,..,28; worst
// 2-way aliasing = free). R13's 640 stride put every row at bank 0 ->
// 8-way conflict on the two V b128 reads per step (6.5M conflict cycles).

// ====== K1: fused x-transpose + bf16 convert + QKV GEMM (R13-proven) ====
__global__ __launch_bounds__(256) void qkvx(
    const float* __restrict__ x, const float* __restrict__ lw_in,
    const float* __restrict__ gw_in, const float* __restrict__ lb_in,
    const float* __restrict__ gb_in, u16* __restrict__ QKV,
    u16* __restrict__ KTg, u16* __restrict__ VTg) {
  __shared__ __align__(16) float xs[32][68];
  __shared__ __align__(16) u16 XTs[32 * 64];   // XOR-swizzled [tok][d]
  const int t = threadIdx.x;
  const int b = blockIdx.x / 40, l0 = (blockIdx.x % 40) * 32;
  for (int i = t; i < 2048; i += 256) {
    const int d = i >> 5, tok = i & 31;
    xs[tok][d] = x[(b * 64 + d) * 1280 + l0 + tok];
  }
  __syncthreads();
  {
    const int tok = t >> 3, c8 = (t & 7) * 8;
    union { bf16x8 v; u32 u[4]; } o;
    const float* src = &xs[tok][c8];
    o.u[0] = pk2(src[0], src[1]); o.u[1] = pk2(src[2], src[3]);
    o.u[2] = pk2(src[4], src[5]); o.u[3] = pk2(src[6], src[7]);
    const int byteoff = (tok * 128 + c8 * 2) ^ ((tok & 7) << 4);
    *(bf16x8*)((char*)XTs + byteoff) = o.v;
  }
  __syncthreads();
  const int lane = t & 63, w = RFL(t >> 6);
  const int lr = lane & 15, lg = lane >> 4;
  const int n0 = w * 96;                        // 4 waves x 96 cols
  bf16x8 a[2][2];
#pragma unroll
  for (int mt = 0; mt < 2; ++mt)
#pragma unroll
    for (int ks = 0; ks < 2; ++ks) {
      const int row = mt * 16 + lr;
      const int abyte = (row * 128 + ks * 64 + lg * 16) ^ ((row & 7) << 4);
      a[mt][ks] = *(const bf16x8*)((char*)XTs + abyte);
    }
  const float* W32 = (n0 < 192) ? lw_in : gw_in;
  const int nb = (n0 < 192) ? n0 : n0 - 192;
  bf16x8 bb[6][2];
#pragma unroll
  for (int nt = 0; nt < 6; ++nt)
#pragma unroll
    for (int ks = 0; ks < 2; ++ks) {
      const float* src = W32 + (nb + nt * 16 + lr) * 64 + ks * 32 + lg * 8;
      const float4 f0 = *(const float4*)src;
      const float4 f1 = *(const float4*)(src + 4);
      union { bf16x8 v; u32 u[4]; } o;
      o.u[0] = pk2(f0.x, f0.y); o.u[1] = pk2(f0.z, f0.w);
      o.u[2] = pk2(f1.x, f1.y); o.u[3] = pk2(f1.z, f1.w);
      bb[nt][ks] = o.v;
    }
  f32x4 acc[2][6];
#pragma unroll
  for (int mt = 0; mt < 2; ++mt)
#pragma unroll
    for (int nt = 0; nt < 6; ++nt) {
      f32x4 z = {0.f, 0.f, 0.f, 0.f};
      acc[mt][nt] = z;
#pragma unroll
      for (int ks = 0; ks < 2; ++ks)
        acc[mt][nt] = MF(a[mt][ks], bb[nt][ks], acc[mt][nt]);
    }
#pragma unroll
  for (int nt = 0; nt < 6; ++nt) {
    const int col = n0 + nt * 16 + lr;
    const float bias = (col < 192) ? lb_in[col] : gb_in[col - 192];
    if (col < 256) {
      // local Q: 1/sqrt(8); global Q: 1/sqrt(8)*log2e*128 (magic-bias)
      const float scale = (col < 64) ? 0.35355339059327373f
                        : ((col >= 192) ? 65.29332172878775f : 1.f);
#pragma unroll
      for (int mt = 0; mt < 2; ++mt)
#pragma unroll
        for (int r = 0; r < 4; ++r) {
          const int row = b * 1280 + l0 + mt * 16 + 4 * lg + r;
          QKV[row * 384 + col] = f2bf((acc[mt][nt][r] + bias) * scale);
        }
    } else if (col < 320) {
      // K-global -> KTg, pre-permuted rows (swap lg bits = bit2<->3 swap)
      const int h = (col - 256) >> 3, d = (col - 256) & 7;
      const int lgp = ((lg & 1) << 1) | (lg >> 1);
#pragma unroll
      for (int mt = 0; mt < 2; ++mt)
#pragma unroll
        for (int r = 0; r < 4; ++r) {
          const int prow = l0 + mt * 16 + 4 * lgp + r;
          KTg[((b * 8 + h) * 1280 + prow) * 8 + d] =
              f2bf(acc[mt][nt][r] + bias);
        }
    } else {
      // V-global -> VTg transposed; pack 4 consecutive tokens per store
      const int h = (col - 320) >> 3, d = (col - 320) & 7;
      const int rowbase = ((b * 8 + h) * 8 + d) * 1280;
#pragma unroll
      for (int mt = 0; mt < 2; ++mt) {
        const int tok = l0 + mt * 16 + 4 * lg;
        uint2 pv;
        pv.x = pk2(acc[mt][nt][0] + bias, acc[mt][nt][1] + bias);
        pv.y = pk2(acc[mt][nt][2] + bias, acc[mt][nt][3] + bias);
        *(uint2*)(VTg + rowbase + tok) = pv;
      }
    }
  }
}

// ====== K2: fused attention launch (R13 structure, VT stride 648) ========
__global__ __launch_bounds__(256) void attn(
    const u16* __restrict__ QKV, const u16* __restrict__ KTg,
    const u16* __restrict__ VTg, u16* __restrict__ AOl,
    float* __restrict__ OSUM, float* __restrict__ OACC8,
    const float* __restrict__ lw_out, const float* __restrict__ gw_out,
    const float* __restrict__ w1, const float* __restrict__ w2,
    u16* __restrict__ Wlout, u16* __restrict__ Wgout,
    u16* __restrict__ W1b, u16* __restrict__ W2b) {
  __shared__ __align__(16) u16 Klds[640 * 8];   // pre-permuted K rows
  __shared__ __align__(16) u16 VT[9 * 648];     // V^T d=0..7; row 8 = ones
  const int t = threadIdx.x;
  if (blockIdx.x < 20) {
    const int bh = blockIdx.y;
    const int b = bh >> 3, h = bh & 7;
    const int split = blockIdx.x & 1, qblk = blockIdx.x >> 1;
    const int k0 = split * 640;
    const uint4* Ksrc = (const uint4*)(KTg + (bh * 1280 + k0) * 8);
    uint4* K4 = (uint4*)Klds;
    for (int i = t; i < 640; i += 256) K4[i] = Ksrc[i];
    const uint4* Vsrc = (const uint4*)(VTg + bh * 8 * 1280);
    uint4* V4 = (uint4*)VT;
    for (int i = t; i < 640; i += 256) {
      const int d = i / 80, j = i % 80;         // dst rows stride 81 uint4
      V4[d * 81 + j] = Vsrc[d * 160 + split * 80 + j];
    }
    for (int l = t; l < 648; l += 256) VT[8 * 648 + l] = 0x3F80;  // ones
    __syncthreads();
    const int lane = t & 63, w = RFL(t >> 6);
    const int c = lane & 31, hi = lane >> 5;
    const int q = qblk * 128 + w * 32 + c;
    const bf16x8 qv = *(const bf16x8*)(QKV + (b * 1280 + q) * 384 + 192 + h * 8);
    const bf16x8 qz = {0, 0, 0, 0, 0, 0, 0, 0};
    const bf16x8 qf = (hi == 0) ? qv : qz;     // zero k-dims 8..15
    const u16* kp = Klds + c * 8;              // A row c (2-lane bcast)
    const int vrow = (c < 8) ? c : 8;
    const u16* vp = VT + vrow * 648 + hi * 8;
    f32x16 oaccA, oaccB, cmagic;
    const float CM = 12582912.0f + 16250.3f;   // 1.5*2^23 + Schraudolph C
#pragma unroll
    for (int i = 0; i < 16; ++i) { oaccA[i] = 0.f; oaccB[i] = 0.f; cmagic[i] = CM; }
    auto step = [&](f32x16& oacc) {
      bf16x8 kf = *(const bf16x8*)kp;          // 32 keys x dims 0..7
      f32x16 s = MF32(kf, qf, cmagic);         // 1.5*2^23 + C + 128*score
      union { f32x16 f; u32 b[16]; } sb; sb.f = s;
      union { u32 u[4]; bf16x8 v; } pb1, pb2;  // B-frags, keys in-order
      pb1.u[0] = __builtin_amdgcn_perm(sb.b[1], sb.b[0], 0x05040100);
      pb1.u[1] = __builtin_amdgcn_perm(sb.b[3], sb.b[2], 0x05040100);
      pb1.u[2] = __builtin_amdgcn_perm(sb.b[5], sb.b[4], 0x05040100);
      pb1.u[3] = __builtin_amdgcn_perm(sb.b[7], sb.b[6], 0x05040100);
      pb2.u[0] = __builtin_amdgcn_perm(sb.b[9], sb.b[8], 0x05040100);
      pb2.u[1] = __builtin_amdgcn_perm(sb.b[11], sb.b[10], 0x05040100);
      pb2.u[2] = __builtin_amdgcn_perm(sb.b[13], sb.b[12], 0x05040100);
      pb2.u[3] = __builtin_amdgcn_perm(sb.b[15], sb.b[14], 0x05040100);
      bf16x8 vf1 = *(const bf16x8*)vp;         // V^T keys +8hi+0..7
      oacc = MF32(vf1, pb1.v, oacc);
      bf16x8 vf2 = *(const bf16x8*)(vp + 16);  // keys +16+8hi+0..7
      oacc = MF32(vf2, pb2.v, oacc);
      kp += 256; vp += 32;
    };
#pragma unroll 2
    for (int jt2 = 0; jt2 < 10; ++jt2) {       // 20 key-tiles, dual acc
      step(oaccA);
      step(oaccB);
    }
    f32x16 oacc;
#pragma unroll
    for (int i = 0; i < 16; ++i) oacc[i] = oaccA[i] + oaccB[i];
    const int qi = bh * 1280 + q;
    if (hi == 0) OSUM[split * 163840 + qi] = oacc[4];  // D[8][c] partial sum
    f32x4 od = {oacc[0], oacc[1], oacc[2], oacc[3]};   // d = 4hi + r
    *(f32x4*)(OACC8 + split * 1310720 + qi * 8 + hi * 4) = od;
    return;
  }
  const int lid = (blockIdx.x - 20) * 128 + blockIdx.y;
  if (lid < 640) {
    // ---- local windowed attention (WIN=5, Q pre-scaled) ----
    const int g = lid * 256 + t;
    const int qi = g % 5, h = (g / 5) & 7, wi = (g / 40) & 255, b = g / 10240;
    const int row = b * 1280 + wi * 5 + qi;
    float q[8];
    {
      bf16x8 qv = *(const bf16x8*)(QKV + row * 384 + h * 8);
#pragma unroll
      for (int d = 0; d < 8; ++d) q[d] = bf2f((u16)qv[d]);
    }
    float p[5], sum = 0.f;
#pragma unroll
    for (int j = 0; j < 5; ++j) {
      const int krow = b * 1280 + wi * 5 + j;
      bf16x8 kv = *(const bf16x8*)(QKV + krow * 384 + 64 + h * 8);
      float s = 0.f;
#pragma unroll
      for (int d = 0; d < 8; ++d) s = fmaf(q[d], bf2f((u16)kv[d]), s);
      p[j] = __expf(s); sum += p[j];
    }
    const float inv = 1.f / sum;
    float o[8] = {0, 0, 0, 0, 0, 0, 0, 0};
#pragma unroll
    for (int j = 0; j < 5; ++j) {
      const int vrow = b * 1280 + wi * 5 + j;
      bf16x8 vv = *(const bf16x8*)(QKV + vrow * 384 + 128 + h * 8);
#pragma unroll
      for (int d = 0; d < 8; ++d) o[d] = fmaf(p[j], bf2f((u16)vv[d]), o[d]);
    }
    union { bf16x8 v; u32 u[4]; } ov;
    ov.u[0] = pk2(o[0] * inv, o[1] * inv); ov.u[1] = pk2(o[2] * inv, o[3] * inv);
    ov.u[2] = pk2(o[4] * inv, o[5] * inv); ov.u[3] = pk2(o[6] * inv, o[7] * inv);
    *(bf16x8*)(AOl + row * 64 + h * 8) = ov.v;
  } else if (lid < 736) {
    // ---- tail weight conversion ----
    const int f = (lid - 640) * 256 + t;
    if (f < 4096)       Wlout[f] = f2bf(lw_out[f]);
    else if (f < 8192)  Wgout[f - 4096] = f2bf(gw_out[f - 4096]);
    else if (f < 16384) W1b[f - 8192] = f2bf(w1[f - 8192]);
    else if (f < 24576) W2b[f - 16384] = f2bf(w2[f - 16384]);
  }
}

// ====== K3: combine splits + proj+res+LN (x2) + gate + FFN + LN3 =========
__global__ __launch_bounds__(64) void tail_kernel(
    const u16* __restrict__ AOl,
    const float* __restrict__ OSUM, const float* __restrict__ OACC8,
    const u16* __restrict__ Wlout, const u16* __restrict__ Wgout,
    const u16* __restrict__ W1b, const u16* __restrict__ W2b,
    const float* __restrict__ lb_out, const float* __restrict__ gb_out,
    const float* __restrict__ lwt,
    const float* __restrict__ g1, const float* __restrict__ b1,
    const float* __restrict__ g2, const float* __restrict__ b2,
    const float* __restrict__ g3, const float* __restrict__ b3,
    const float* __restrict__ bf1, const float* __restrict__ bf2,
    const float* __restrict__ x, float* __restrict__ out) {
  __shared__ __align__(16) float xso[64][20];   // residual in, out^T at end
  __shared__ __align__(16) u16 Ft[16 * 64];     // fused (XOR-swizzled)
  __shared__ __align__(16) u16 Ht[16 * 128];    // ffn hidden (XOR-swizzled)
  const int t = threadIdx.x;
  const int b = blockIdx.y, l0 = blockIdx.x * 16;
  for (int i = t; i < 1024; i += 64) {
    const int d = i >> 4, tok = i & 15;
    xso[d][tok] = x[(b * 64 + d) * 1280 + l0 + tok];
  }
  __syncthreads();
  const int lr = t & 15, lg = (t & 63) >> 4;
  const int grow = b * 1280 + l0;

  f32x4 accl[4], accg[4];
#pragma unroll
  for (int nt = 0; nt < 4; ++nt) { f32x4 z = {0,0,0,0}; accl[nt] = z; accg[nt] = z; }
#pragma unroll
  for (int ks = 0; ks < 2; ++ks) {
    bf16x8 al = *(const bf16x8*)(AOl + (grow + lr) * 64 + ks * 32 + lg * 8);
    const int h = ks * 4 + lg;
    const int qi = (b * 8 + h) * 1280 + l0 + lr;
    f32x4 oa0 = *(const f32x4*)(OACC8 + qi * 8);
    f32x4 oa1 = *(const f32x4*)(OACC8 + qi * 8 + 4);
    f32x4 ob0 = *(const f32x4*)(OACC8 + 1310720 + qi * 8);
    f32x4 ob1 = *(const f32x4*)(OACC8 + 1310720 + qi * 8 + 4);
    const float inv = 1.f / (OSUM[qi] + OSUM[163840 + qi]);
    union { bf16x8 v; u32 u[4]; } agv;
    agv.u[0] = pk2((oa0[0] + ob0[0]) * inv, (oa0[1] + ob0[1]) * inv);
    agv.u[1] = pk2((oa0[2] + ob0[2]) * inv, (oa0[3] + ob0[3]) * inv);
    agv.u[2] = pk2((oa1[0] + ob1[0]) * inv, (oa1[1] + ob1[1]) * inv);
    agv.u[3] = pk2((oa1[2] + ob1[2]) * inv, (oa1[3] + ob1[3]) * inv);
#pragma unroll
    for (int nt = 0; nt < 4; ++nt) {
      bf16x8 bl = *(const bf16x8*)(Wlout + (nt * 16 + lr) * 64 + ks * 32 + lg * 8);
      bf16x8 bg = *(const bf16x8*)(Wgout + (nt * 16 + lr) * 64 + ks * 32 + lg * 8);
      accl[nt] = MF(al, bl, accl[nt]);
      accg[nt] = MF(agv.v, bg, accg[nt]);
    }
  }
#pragma unroll
  for (int nt = 0; nt < 4; ++nt) {
    const int col = nt * 16 + lr;
    const float bl = lb_out[col], bg = gb_out[col];
    f32x4 xr = *(const f32x4*)&xso[col][lg * 4];
#pragma unroll
    for (int r = 0; r < 4; ++r) {
      accl[nt][r] += bl + xr[r];
      accg[nt][r] += bg + xr[r];
    }
  }
  auto LN = [&](f32x4* a, const float* gam, const float* bet) {
    float gv[4], bv[4];
#pragma unroll
    for (int nt = 0; nt < 4; ++nt) { gv[nt] = gam[nt * 16 + lr]; bv[nt] = bet[nt * 16 + lr]; }
#pragma unroll
    for (int r = 0; r < 4; ++r) {
      float s = a[0][r] + a[1][r] + a[2][r] + a[3][r];
      s += __shfl_xor(s, 1); s += __shfl_xor(s, 2);
      s += __shfl_xor(s, 4); s += __shfl_xor(s, 8);
      const float mu = s * 0.015625f;
      float q = 0.f;
#pragma unroll
      for (int nt = 0; nt < 4; ++nt) { const float cv = a[nt][r] - mu; q = fmaf(cv, cv, q); }
      q += __shfl_xor(q, 1); q += __shfl_xor(q, 2);
      q += __shfl_xor(q, 4); q += __shfl_xor(q, 8);
      const float rsq = rsqrtf(q * 0.015625f + 1e-5f);
#pragma unroll
      for (int nt = 0; nt < 4; ++nt)
        a[nt][r] = (a[nt][r] - mu) * rsq * gv[nt] + bv[nt];
    }
  };
  LN(accl, g1, b1);
  LN(accg, g2, b2);
  f32x4 fus[4];
#pragma unroll
  for (int nt = 0; nt < 4; ++nt) {
    const int col = nt * 16 + lr;
    const float al_ = 1.f / (1.f + __expf(-lwt[col]));
#pragma unroll
    for (int r = 0; r < 4; ++r)
      fus[nt][r] = al_ * accl[nt][r] + (1.f - al_) * accg[nt][r];
  }
#pragma unroll
  for (int nt = 0; nt < 4; ++nt)
#pragma unroll
    for (int r = 0; r < 4; ++r) {
      const int ltok = lg * 4 + r;
      const int byteoff = (ltok * 128 + (nt * 16 + lr) * 2) ^ ((ltok & 7) << 4);
      *(u16*)((char*)Ft + byteoff) = f2bf(fus[nt][r]);
    }
  asm volatile("" ::: "memory");
  __syncthreads();
  f32x4 hcc[8];
#pragma unroll
  for (int nt = 0; nt < 8; ++nt) { f32x4 z = {0,0,0,0}; hcc[nt] = z; }
#pragma unroll
  for (int ks = 0; ks < 2; ++ks) {
    const int abyte = (lr * 128 + ks * 64 + lg * 16) ^ ((lr & 7) << 4);
    bf16x8 af = *(const bf16x8*)((char*)Ft + abyte);
#pragma unroll
    for (int nt = 0; nt < 8; ++nt) {
      bf16x8 bw = *(const bf16x8*)(W1b + (nt * 16 + lr) * 64 + ks * 32 + lg * 8);
      hcc[nt] = MF(af, bw, hcc[nt]);
    }
  }
#pragma unroll
  for (int nt = 0; nt < 8; ++nt) {
    const int f = nt * 16 + lr;
    const float bbv = bf1[f];
#pragma unroll
    for (int r = 0; r < 4; ++r) {
      const float v = fmaxf(hcc[nt][r] + bbv, 0.f);
      const int ltok = lg * 4 + r;
      const int byteoff = (ltok * 256 + f * 2) ^ ((ltok & 7) << 4);
      *(u16*)((char*)Ht + byteoff) = f2bf(v);
    }
  }
  asm volatile("" ::: "memory");
  f32x4 occ[4];
#pragma unroll
  for (int nt = 0; nt < 4; ++nt) { f32x4 z = {0,0,0,0}; occ[nt] = z; }
#pragma unroll
  for (int ks = 0; ks < 4; ++ks) {
    const int abyte = (lr * 256 + ks * 64 + lg * 16) ^ ((lr & 7) << 4);
    bf16x8 af = *(const bf16x8*)((char*)Ht + abyte);
#pragma unroll
    for (int nt = 0; nt < 4; ++nt) {
      bf16x8 bw = *(const bf16x8*)(W2b + (nt * 16 + lr) * 128 + ks * 32 + lg * 8);
      occ[nt] = MF(af, bw, occ[nt]);
    }
  }
#pragma unroll
  for (int nt = 0; nt < 4; ++nt) {
    const float bb2 = bf2[nt * 16 + lr];
#pragma unroll
    for (int r = 0; r < 4; ++r) occ[nt][r] += bb2 + fus[nt][r];
  }
  LN(occ, g3, b3);
#pragma unroll
  for (int nt = 0; nt < 4; ++nt)
#pragma unroll
    for (int r = 0; r < 4; ++r)
      xso[nt * 16 + lr][lg * 4 + r] = occ[nt][r];
  __syncthreads();
  for (int i = t; i < 1024; i += 64) {
    const int d = i >> 4, tok = i & 15;
    out[(b * 64 + d) * 1280 + l0 + tok] = xso[d][tok];
  }
}

extern "C" void kernel_launch(void* const* d_in, const int* in_sizes, int n_in,
                              void* d_out, int out_size, void* d_ws,
                              size_t ws_size, hipStream_t stream) {
  const float* x      = (const float*)d_in[0];
  const float* lw_in  = (const float*)d_in[1];
  const float* lb_in  = (const float*)d_in[2];
  const float* lw_out = (const float*)d_in[3];
  const float* lb_out = (const float*)d_in[4];
  const float* gw_in  = (const float*)d_in[5];
  const float* gb_in  = (const float*)d_in[6];
  const float* gw_out = (const float*)d_in[7];
  const float* gb_out = (const float*)d_in[8];
  const float* lwt    = (const float*)d_in[9];
  const float* g1 = (const float*)d_in[10]; const float* b1 = (const float*)d_in[11];
  const float* g2 = (const float*)d_in[12]; const float* b2 = (const float*)d_in[13];
  const float* g3 = (const float*)d_in[14]; const float* b3 = (const float*)d_in[15];
  const float* w1 = (const float*)d_in[16]; const float* bf1 = (const float*)d_in[17];
  const float* w2 = (const float*)d_in[18]; const float* bf2 = (const float*)d_in[19];
  float* out = (float*)d_out;

  u16* QKV   = (u16*)d_ws;            // 7,864,320 u16
  u16* AOl   = QKV + 7864320;         // 1,310,720 u16
  u16* KTg   = AOl + 1310720;         // 1,310,720 u16
  u16* VTg   = KTg + 1310720;         // 1,310,720 u16
  u16* Wlout = VTg + 1310720;         // 4,096
  u16* Wgout = Wlout + 4096;          // 4,096
  u16* W1b   = Wgout + 4096;          // 8,192
  u16* W2b   = W1b + 8192;            // 8,192
  float* OSUM  = (float*)(W2b + 8192);    // 2 x 163,840 f32
  float* OACC8 = OSUM + 327680;           // 2 x 1,310,720 f32

  qkvx<<<dim3(640), dim3(256), 0, stream>>>(x, lw_in, gw_in, lb_in, gb_in,
                                            QKV, KTg, VTg);
  attn<<<dim3(26, 128), dim3(256), 0, stream>>>(QKV, KTg, VTg, AOl, OSUM,
                                                OACC8, lw_out, gw_out, w1, w2,
                                                Wlout, Wgout, W1b, W2b);
  tail_kernel<<<dim3(80, 16), dim3(64), 0, stream>>>(
      AOl, OSUM, OACC8, Wlout, Wgout, W1b, W2b, lb_out, gb_out, lwt,
      g1, b1, g2, b2, g3, b3, bf1, bf2, x, out);
}